// Round 4
// baseline (154.375 us; speedup 1.0000x reference)
//
#include <hip/hip_runtime.h>
#include <math.h>

#define DIM 128
#define BATCH 8192
#define NTRIP (2 * BATCH)      // 16384
#define NREL 500
#define MARGIN 1.0f

typedef __attribute__((ext_vector_type(8))) short short8;
typedef __attribute__((ext_vector_type(4))) float f32x4;

__device__ __forceinline__ float wave_sum(float v) {
    v += __shfl_xor(v, 32, 64);
    v += __shfl_xor(v, 16, 64);
    v += __shfl_xor(v, 8, 64);
    v += __shfl_xor(v, 4, 64);
    v += __shfl_xor(v, 2, 64);
    v += __shfl_xor(v, 1, 64);
    return v;
}

__device__ __forceinline__ float quad_sum(float v) {
    // reduce over the 16 cols held in lane&15 (same quad)
    v += __shfl_xor(v, 1, 64);
    v += __shfl_xor(v, 2, 64);
    v += __shfl_xor(v, 4, 64);
    v += __shfl_xor(v, 8, 64);
    return v;
}

// exact fp32 -> bf16 round-to-nearest-even (finite values)
__device__ __forceinline__ short f2bf(float f) {
    unsigned u = __float_as_uint(f);
    u = (u + 0x7fffu + ((u >> 16) & 1u)) >> 16;
    return (short)u;
}

// ---- K1: per-relation Mr -> bf16 transposed global buffer, + count ------
// Block = relation. Also grid-strides the relation histogram (blocks 0..63).
__global__ __launch_bounds__(256)
void transr_prep(const int* __restrict__ pos, const int* __restrict__ neg,
                 const float* __restrict__ transfer,
                 int* __restrict__ rel_count, short* __restrict__ bt_g) {
    const int rel = blockIdx.x;
    const int tid = threadIdx.x;

    const int gid = rel * 256 + tid;
    if (gid < NTRIP) {
        const int r = (gid < BATCH) ? pos[gid * 3 + 1] : neg[(gid - BATCH) * 3 + 1];
        atomicAdd(&rel_count[r], 1);
    }

    // Bt[col][k] = bf16(Mr[k][col]); reads coalesced over col (lanes)
    const int col = tid & 127;
    const int kh = tid >> 7;                    // 0/1 -> k halves
    const float* __restrict__ mr = transfer + (size_t)rel * (DIM * DIM);
    short* __restrict__ outp = bt_g + (size_t)rel * (DIM * DIM) + col * DIM + kh * 64;
#pragma unroll
    for (int j0 = 0; j0 < 64; j0 += 8) {
        short8 v;
#pragma unroll
        for (int jj = 0; jj < 8; ++jj)
            v[jj] = f2bf(mr[(size_t)(kh * 64 + j0 + jj) * DIM + col]);
        *(short8*)(outp + j0) = v;
    }
}

// ---- K2: exclusive scan of counts -> offsets + cursors ------------------
__global__ __launch_bounds__(512)
void transr_scan(const int* __restrict__ rel_count, int* __restrict__ rel_off,
                 int* __restrict__ rel_cur) {
    __shared__ int s[512];
    const int t = threadIdx.x;
    const int c = (t < NREL) ? rel_count[t] : 0;
    s[t] = c;
    __syncthreads();
    for (int o = 1; o < 512; o <<= 1) {
        int v = s[t];
        if (t >= o) v += s[t - o];
        __syncthreads();
        s[t] = v;
        __syncthreads();
    }
    const int excl = s[t] - c;
    if (t <= NREL) rel_off[t] = (t == NREL) ? NTRIP : excl;
    if (t < NREL) rel_cur[t] = excl;
}

// ---- K3: scatter triple ids into relation-grouped order -----------------
__global__ __launch_bounds__(256)
void transr_scatter(const int* __restrict__ pos, const int* __restrict__ neg,
                    int* __restrict__ rel_cur, int* __restrict__ sorted) {
    const int i = blockIdx.x * 256 + threadIdx.x;
    if (i >= NTRIP) return;
    const int r = (i < BATCH) ? pos[i * 3 + 1] : neg[(i - BATCH) * 3 + 1];
    const int slot = atomicAdd(&rel_cur[r], 1);
    sorted[slot] = i;
}

// ---- K4: main scoring (bf16 MFMA, B from global) + fused loss -----------
// A rows: row = 2*triple + (0=h,1=t)  ->  h'/t' land in adjacent acc regs.
__global__ __launch_bounds__(256)
void transr_main(const int* __restrict__ pos, const int* __restrict__ neg,
                 const float* __restrict__ entities,
                 const float* __restrict__ relations,
                 const short* __restrict__ bt_g,
                 const int* __restrict__ rel_off, const int* __restrict__ sorted,
                 float* __restrict__ scores, int* __restrict__ done,
                 float* __restrict__ out) {
    __shared__ float rhat_s[DIM];
    __shared__ float lred[4];
    __shared__ int lflag;

    const int rel = blockIdx.x;
    const int tid = threadIdx.x;
    const int begin = rel_off[rel], end = rel_off[rel + 1];
    const int cnt = end - begin;

    if (tid < DIM) rhat_s[tid] = relations[(size_t)rel * DIM + tid];
    __syncthreads();
    if (tid < 64) {
        const float a = rhat_s[tid], b = rhat_s[tid + 64];
        const float ss = wave_sum(fmaf(a, a, b * b));
        if (tid == 0) lred[0] = 1.0f / fmaxf(sqrtf(ss), 1e-12f);
    }
    __syncthreads();
    const float rinv = lred[0];

    const int lane = tid & 63;
    const int w = tid >> 6;
    const int n = lane & 15;          // A-row id / C-col / B-col low bits
    const int q = lane >> 4;          // quad
    const int jm = n >> 1;            // triple within tile (A side)
    const int sel = n & 1;            // 0=head, 1=tail

    float r_reg[8];
#pragma unroll
    for (int nt = 0; nt < 8; ++nt) r_reg[nt] = rhat_s[nt * 16 + n] * rinv;

    const short* __restrict__ bt_rel = bt_g + (size_t)rel * (DIM * DIM);
    const int ntiles = (cnt + 7) >> 3;

    for (int tile = w; tile < ntiles; tile += 4) {
        int idxA = begin + tile * 8 + jm;
        if (idxA >= end) idxA = end - 1;          // clamp: duplicates are benign
        const int idA = sorted[idxA];
        const int* trip = (idA < BATCH) ? (pos + idA * 3) : (neg + (idA - BATCH) * 3);
        const float* __restrict__ erow = entities + (size_t)trip[sel ? 2 : 0] * DIM;

        short8 af[4];
#pragma unroll
        for (int kc = 0; kc < 4; ++kc) {
            const float4 u0 = *(const float4*)(erow + kc * 32 + q * 8);
            const float4 u1 = *(const float4*)(erow + kc * 32 + q * 8 + 4);
            short8 a;
            a[0] = f2bf(u0.x); a[1] = f2bf(u0.y); a[2] = f2bf(u0.z); a[3] = f2bf(u0.w);
            a[4] = f2bf(u1.x); a[5] = f2bf(u1.y); a[6] = f2bf(u1.z); a[7] = f2bf(u1.w);
            af[kc] = a;
        }

        f32x4 acc[8];
#pragma unroll
        for (int nt = 0; nt < 8; ++nt) acc[nt] = (f32x4){0.0f, 0.0f, 0.0f, 0.0f};
#pragma unroll
        for (int nt = 0; nt < 8; ++nt) {
            const short* __restrict__ bp = bt_rel + (nt * 16 + n) * DIM + q * 8;
#pragma unroll
            for (int kc = 0; kc < 4; ++kc) {
                const short8 bfr = *(const short8*)(bp + kc * 32);
                acc[nt] = __builtin_amdgcn_mfma_f32_16x16x32_bf16(af[kc], bfr, acc[nt], 0, 0, 0);
            }
        }

        // epilogue: reg pairs (0,1)=triple 2q, (2,3)=triple 2q+1 (h,t adjacent)
#pragma unroll
        for (int p = 0; p < 4; p += 2) {
            float hs = 0.0f, ts = 0.0f;
#pragma unroll
            for (int nt = 0; nt < 8; ++nt) {
                hs = fmaf(acc[nt][p], acc[nt][p], hs);
                ts = fmaf(acc[nt][p + 1], acc[nt][p + 1], ts);
            }
            hs = quad_sum(hs);
            ts = quad_sum(ts);
            const float invh = 1.0f / fmaxf(sqrtf(hs), 1e-12f);
            const float invt = 1.0f / fmaxf(sqrtf(ts), 1e-12f);
            float ss = 0.0f;
#pragma unroll
            for (int nt = 0; nt < 8; ++nt)
                ss += fabsf(fmaf(acc[nt][p], invh, r_reg[nt]) - acc[nt][p + 1] * invt);
            ss = quad_sum(ss);
            if (n == 0) {
                int idxS = begin + tile * 8 + (q * 2 + (p >> 1));
                if (idxS >= end) idxS = end - 1;
                __hip_atomic_store(&scores[sorted[idxS]], ss,
                                   __ATOMIC_RELAXED, __HIP_MEMORY_SCOPE_AGENT);
            }
        }
    }

    // completion protocol + fused loss in the last-finishing block
    __syncthreads();
    if (tid == 0) {
        __threadfence();
        const int old = atomicAdd(done, 1);
        lflag = (old == NREL - 1) ? 1 : 0;
    }
    __syncthreads();
    if (lflag) {
        __threadfence();
        float ss = 0.0f;
        for (int i = tid; i < BATCH; i += 256) {
            const float a = __hip_atomic_load(&scores[i], __ATOMIC_RELAXED, __HIP_MEMORY_SCOPE_AGENT);
            const float b = __hip_atomic_load(&scores[BATCH + i], __ATOMIC_RELAXED, __HIP_MEMORY_SCOPE_AGENT);
            const float d = a - b + MARGIN;
            ss += (d > 0.0f) ? d : 0.0f;
        }
        ss = wave_sum(ss);
        if (lane == 0) lred[w] = ss;
        __syncthreads();
        if (tid == 0) out[0] = (lred[0] + lred[1] + lred[2] + lred[3]) * (1.0f / (float)BATCH);
    }
}

extern "C" void kernel_launch(void* const* d_in, const int* in_sizes, int n_in,
                              void* d_out, int out_size, void* d_ws, size_t ws_size,
                              hipStream_t stream) {
    const int*   pos       = (const int*)d_in[0];
    const int*   neg       = (const int*)d_in[1];
    const float* entities  = (const float*)d_in[2];
    const float* relations = (const float*)d_in[3];
    const float* transfer  = (const float*)d_in[4];
    float* out = (float*)d_out;

    // workspace layout (4B units)
    int*   wsi       = (int*)d_ws;
    float* scores    = (float*)d_ws;        // [0, 16384)
    int*   rel_off   = wsi + 16384;         // [16384, 16885)
    int*   rel_cur   = wsi + 16896;         // [16896, 17408)
    int*   rel_count = wsi + 17408;         // [17408, 17920)
    int*   done      = wsi + 17920;         // [17920]
    int*   sorted    = wsi + 18432;         // [18432, 34816)
    short* bt_g      = (short*)(wsi + 36864); // 500*128*128 bf16 = 16.4 MB

    // zero rel_count[512] + done in one tiny fill
    hipMemsetAsync(rel_count, 0, 513 * sizeof(int), stream);
    transr_prep<<<NREL, 256, 0, stream>>>(pos, neg, transfer, rel_count, bt_g);
    transr_scan<<<1, 512, 0, stream>>>(rel_count, rel_off, rel_cur);
    transr_scatter<<<(NTRIP + 255) / 256, 256, 0, stream>>>(pos, neg, rel_cur, sorted);
    transr_main<<<NREL, 256, 0, stream>>>(pos, neg, entities, relations, bt_g,
                                          rel_off, sorted, scores, done, out);
}